// Round 6
// baseline (268.454 us; speedup 1.0000x reference)
//
#include <hip/hip_runtime.h>
#include <stdint.h>

// MultiHeadAttention: B=8, N=1024 (32x32 tokens), E=1024, H=16, D=64.
// Pipeline: cvt(x,wqkv,wout) -> bias_precomp -> gemm_qkv -> fused attn -> gemm_out.
// All GEMM-shaped compute on v_mfma_f32_16x16x32_bf16 (fp32 accum).
// Fragment maps (learn_hip m89/m91/m120):
//   A: lane holds A[m=lane&15][k=8*(lane>>4)+t]   (contiguous 16B -> ds_read_b128)
//   B: lane holds B[k=8*(lane>>4)+t][n=lane&15]
//   C/D: col=lane&15, row=4*(lane>>4)+reg
// R6 attn: 2-barrier double-buffered K-loop. R5 exposed the full staging
// latency 8x/block (issue immediately before the draining barrier, 4 barriers
// per js). Now: sK[2]+sV[2]+sP = 80KB (2 blocks/CU); prefetch K/V[js+1] right
// after B1; S-phase reads sK[cur] directly (no hoist/alias barrier); B2 drains
// the prefetch AFTER the fat S+softmax window. 17 barriers total vs 33.
// Kept (verified): conflict-free P subchunk layout (bank 4*(s^col), 0
// conflicts measured), ones-column MFMA row sums, register-resident Q frags.

#define LOG2E 1.4426950408889634f

typedef __attribute__((ext_vector_type(8))) short short8;
typedef __attribute__((ext_vector_type(4))) short short4v;
typedef __attribute__((ext_vector_type(4))) float floatx4;
typedef __attribute__((ext_vector_type(2))) unsigned int uint2v;

__device__ __forceinline__ short f2bf(float f) {  // RNE, matches HW/numpy
  uint32_t u = __builtin_bit_cast(uint32_t, f);
  u = (u + 0x7FFFu + ((u >> 16) & 1u)) >> 16;
  return (short)(uint16_t)u;
}
__device__ __forceinline__ float bf2f(short s) {
  uint32_t u = ((uint32_t)(uint16_t)s) << 16;
  return __builtin_bit_cast(float, u);
}
__device__ __forceinline__ float fast_exp2(float x) {
#if __has_builtin(__builtin_amdgcn_exp2f)
  return __builtin_amdgcn_exp2f(x);
#else
  return exp2f(x);
#endif
}

__device__ __forceinline__ void gload_lds16(const short* g, short* l) {
  __builtin_amdgcn_global_load_lds(
      (const __attribute__((address_space(1))) void*)g,
      (__attribute__((address_space(3))) void*)l, 16, 0, 0);
}

// ---------------- fp32 -> bf16 convert (vectorized) ----------------
__global__ void cvt_bf16(const float* __restrict__ src, short* __restrict__ dst, int n4) {
  int i = blockIdx.x * 256 + threadIdx.x;
  if (i >= n4) return;
  float4 f = ((const float4*)src)[i];
  short4v o;
  o.x = f2bf(f.x); o.y = f2bf(f.y); o.z = f2bf(f.z); o.w = f2bf(f.w);
  ((short4v*)dst)[i] = o;
}

// ------------- bias table in MFMA C-layout tiles -------------------
// biast[h][a][b][lane][r] = biases[h][|r_i-r_j|*32+|c_i-c_j|] * LOG2E (bf16)
// with row = a*16 + 4*(lane>>4) + r, col = b*16 + (lane&15).
// Symmetric in (row,col), so usable for S^T tiles with a=j-tile, b=i-tile.
__global__ void bias_precomp(const float* __restrict__ biases, short* __restrict__ biast) {
  int t = blockIdx.x * 256 + threadIdx.x;   // [0, 16*64*64*64)
  int lane = t & 63;
  int tile = t >> 6;
  int jt = tile & 63, it = (tile >> 6) & 63, h = tile >> 12;
  int i0 = it * 16 + ((lane >> 4) << 2);
  int j = jt * 16 + (lane & 15);
  int rj = j >> 5, cj = j & 31;
  short4v o;
#pragma unroll
  for (int r = 0; r < 4; r++) {
    int i = i0 + r;
    int ri = i >> 5, ci = i & 31;
    int dr = ri - rj; if (dr < 0) dr = -dr;
    int dc = ci - cj; if (dc < 0) dc = -dc;
    o[r] = f2bf(biases[h * 1024 + dr * 32 + dc] * LOG2E);
  }
  *(short4v*)&biast[(size_t)t * 4] = o;
}

// ---------------- 128x128 tile GEMM, C = A @ Bt^T ------------------
// A [M][1024] bf16 row-major, Bt [N][1024] bf16 row-major (= B transposed).
// MODE 0: QKV epilogue (scatter to q,k [bh][n][64] and vt [bh][64][n], bf16)
// MODE 1: out-proj epilogue (add bvec, fp32 store)
template <int MODE>
__global__ __launch_bounds__(256, 2) void gemm_bt(
    const short* __restrict__ A, const short* __restrict__ Bt,
    short* __restrict__ qo, short* __restrict__ ko, short* __restrict__ vto,
    const float* __restrict__ bvec, float* __restrict__ outf) {
  __shared__ __align__(16) short sA[128 * 64];
  __shared__ __align__(16) short sB[128 * 64];
  const int tid = threadIdx.x;
  const int w = tid >> 6, lane = tid & 63;
  const int wr = w >> 1, wc = w & 1;
  const int bm = blockIdx.y, bn = blockIdx.x;
  const int qd = lane >> 4, col = lane & 15;

  floatx4 acc[4][4] = {};
  const int rowA0 = bm * 128, rowB0 = bn * 128;
  const int ciw = w * 256;

  for (int kk = 0; kk < 1024; kk += 64) {
    __syncthreads();
#pragma unroll
    for (int n = 0; n < 4; n++) {
      int ci = ciw + n * 64 + lane;
      int r = ci >> 3, c = (ci & 7) ^ (r & 7);
      gload_lds16(A + (size_t)(rowA0 + r) * 1024 + kk + c * 8, &sA[ci * 8]);
    }
#pragma unroll
    for (int n = 0; n < 4; n++) {
      int ci = ciw + n * 64 + lane;
      int r = ci >> 3, c = (ci & 7) ^ (r & 7);
      gload_lds16(Bt + (size_t)(rowB0 + r) * 1024 + kk + c * 8, &sB[ci * 8]);
    }
    __syncthreads();

#pragma unroll
    for (int ks = 0; ks < 2; ks++) {
      const int ch = qd + ks * 4;
      short8 af[4], bff[4];
#pragma unroll
      for (int rt = 0; rt < 4; rt++) {
        int r = wr * 64 + rt * 16 + col;
        af[rt] = *(const short8*)&sA[r * 64 + ((ch ^ (r & 7)) << 3)];
      }
#pragma unroll
      for (int ct = 0; ct < 4; ct++) {
        int r = wc * 64 + ct * 16 + col;
        bff[ct] = *(const short8*)&sB[r * 64 + ((ch ^ (r & 7)) << 3)];
      }
#pragma unroll
      for (int rt = 0; rt < 4; rt++)
#pragma unroll
        for (int ct = 0; ct < 4; ct++)
          acc[rt][ct] = __builtin_amdgcn_mfma_f32_16x16x32_bf16(af[rt], bff[ct], acc[rt][ct], 0, 0, 0);
    }
  }

  if (MODE == 0) {
    if (bn >= 16) {
      // V region (block-uniform): pack 4 consecutive n into b64 scatters
#pragma unroll
      for (int rt = 0; rt < 4; rt++) {
#pragma unroll
        for (int ct = 0; ct < 4; ct++) {
          int Cg = bn * 128 + wc * 64 + ct * 16 + col;
          int e = Cg & 1023, h = e >> 6, dd = e & 63;
          short4v pv;
#pragma unroll
          for (int r = 0; r < 4; r++) pv[r] = f2bf(acc[rt][ct][r]);
          int R0 = bm * 128 + wr * 64 + rt * 16 + qd * 4;
          int b = R0 >> 10, n0 = R0 & 1023;
          int bh = b * 16 + h;
          *(short4v*)&vto[((size_t)bh * 64 + dd) * 1024 + n0] = pv;
        }
      }
    } else {
#pragma unroll
      for (int rt = 0; rt < 4; rt++) {
#pragma unroll
        for (int ct = 0; ct < 4; ct++) {
          int Cg = bn * 128 + wc * 64 + ct * 16 + col;
          int which = Cg >> 10, e = Cg & 1023, h = e >> 6, dd = e & 63;
#pragma unroll
          for (int r = 0; r < 4; r++) {
            int R = bm * 128 + wr * 64 + rt * 16 + qd * 4 + r;
            int b = R >> 10, n = R & 1023;
            int bh = b * 16 + h;
            short v = f2bf(acc[rt][ct][r]);
            if (which == 0)
              qo[((size_t)bh * 1024 + n) * 64 + dd] = v;
            else
              ko[((size_t)bh * 1024 + n) * 64 + dd] = v;
          }
        }
      }
    }
  } else {
#pragma unroll
    for (int rt = 0; rt < 4; rt++)
#pragma unroll
      for (int ct = 0; ct < 4; ct++) {
        int Cg = bn * 128 + wc * 64 + ct * 16 + col;
        float bo = bvec[Cg];
#pragma unroll
        for (int r = 0; r < 4; r++) {
          int R = bm * 128 + wr * 64 + rt * 16 + qd * 4 + r;
          outf[(size_t)R * 1024 + Cg] = acc[rt][ct][r] + bo;
        }
      }
  }
}

// ---------------- fused attention (flash-style, no max: logits bounded) ----
// grid.x = bh (128), grid.y = qt (16). Per block: Q-tile 64 rows; 8 K/V tiles
// of 128. S^T = K Q^T (j rows, i cols); Q B-frags in registers.
// LDS: sK[2] 32KB (XOR-8), sV[2] 32KB (XOR-16), sP 16KB (subchunk layout;
// Q staging temp at start). 80KB -> 2 blocks/CU. 2 barriers per js.
__global__ __launch_bounds__(256, 2) void attn_fused(
    const short* __restrict__ q, const short* __restrict__ k,
    const short* __restrict__ vt, const short* __restrict__ biast,
    short* __restrict__ ao) {
  __shared__ __align__(16) short sK[2][128 * 64];
  __shared__ __align__(16) short sV[2][64 * 128];
  __shared__ __align__(16) short sP[64 * 128];
  const int tid = threadIdx.x, w = tid >> 6, lane = tid & 63;
  const int bh = blockIdx.x, qt = blockIdx.y;
  const int h = bh & 15;
  const int qd = lane >> 4, col = lane & 15;
  const short* qb = q + (size_t)bh * 65536;
  const short* kb = k + (size_t)bh * 65536;
  const short* vb = vt + (size_t)bh * 65536;
  const int ciw = w * 256;

  // ---- preloop: stage Q (into sP temp) + K[0] + V[0], then hoist Q frags
#pragma unroll
  for (int n = 0; n < 2; n++) {
    int ci = w * 128 + n * 64 + lane;
    int r = ci >> 3, c = (ci & 7) ^ (r & 7);
    gload_lds16(qb + (size_t)(qt * 64 + r) * 64 + c * 8, &sP[ci * 8]);
  }
#pragma unroll
  for (int n = 0; n < 4; n++) {
    int ci = ciw + n * 64 + lane;
    int r = ci >> 3, c = (ci & 7) ^ (r & 7);
    gload_lds16(kb + (size_t)r * 64 + c * 8, &sK[0][ci * 8]);
  }
#pragma unroll
  for (int n = 0; n < 4; n++) {
    int ci = ciw + n * 64 + lane;
    int r = ci >> 4, c = (ci & 15) ^ (r & 15);
    gload_lds16(vb + (size_t)r * 1024 + c * 8, &sV[0][ci * 8]);
  }
  __syncthreads();  // Q/K0/V0 staged
  short8 bq[2][4];  // [ks][ct] B-frags of Q, js-invariant (32 VGPRs)
#pragma unroll
  for (int ks = 0; ks < 2; ks++) {
    const int ch = qd + ks * 4;
#pragma unroll
    for (int ct = 0; ct < 4; ct++) {
      int r2 = ct * 16 + col;
      bq[ks][ct] = *(const short8*)&sP[r2 * 64 + ((ch ^ (r2 & 7)) << 3)];
    }
  }

  // ones B-frag for row-sum MFMA (bf16 1.0 = 0x3F80)
  short8 onesf;
#pragma unroll
  for (int t = 0; t < 8; t++) onesf[t] = (short)0x3F80;

  floatx4 oacc[4] = {};  // [d-tile ct], O rows i in [16w,16w+16)
  floatx4 osum = {};
  const float SCL = 0.125f * LOG2E;

  for (int js = 0; js < 8; js++) {
    const int cur = js & 1, nxt = cur ^ 1;
    __syncthreads();  // B1: PV[js-1] reads done (js=0: Q-frag reads done);
                      //     prior-iter prefetch (K[js],V[js]) already drained at B2[js-1]
    if (js < 7) {
      // prefetch next K/V tiles; in flight across the whole S+softmax phase
#pragma unroll
      for (int n = 0; n < 4; n++) {
        int ci = ciw + n * 64 + lane;
        int r = ci >> 3, c = (ci & 7) ^ (r & 7);
        gload_lds16(kb + (size_t)((js + 1) * 128 + r) * 64 + c * 8, &sK[nxt][ci * 8]);
      }
#pragma unroll
      for (int n = 0; n < 4; n++) {
        int ci = ciw + n * 64 + lane;
        int r = ci >> 4, c = (ci & 15) ^ (r & 15);
        gload_lds16(vb + (size_t)r * 1024 + (js + 1) * 128 + c * 8, &sV[nxt][ci * 8]);
      }
    }

    // S^T tiles (wave w: j rows [32w,32w+32), i cols 0..64) + softmax + P
    const short* sKc = sK[cur];
#pragma unroll
    for (int rt = 0; rt < 2; rt++) {
      const int a = js * 8 + w * 2 + rt;    // global j-tile
      const int s = w * 8 + rt * 4 + qd;    // P subchunk index (j>>2)
      short4v bfrag[4];
#pragma unroll
      for (int ct = 0; ct < 4; ct++) {
        int b = qt * 4 + ct;                 // global i-tile
        bfrag[ct] = *(const short4v*)&biast[((((size_t)h * 64 + a) * 64 + b) << 8) + lane * 4];
      }
      const int r = w * 32 + rt * 16 + col;
      short8 ak0 = *(const short8*)&sKc[r * 64 + (((qd + 0) ^ (r & 7)) << 3)];
      short8 ak1 = *(const short8*)&sKc[r * 64 + (((qd + 4) ^ (r & 7)) << 3)];
      floatx4 sacc[4] = {};
#pragma unroll
      for (int ct = 0; ct < 4; ct++)
        sacc[ct] = __builtin_amdgcn_mfma_f32_16x16x32_bf16(ak0, bq[0][ct], sacc[ct], 0, 0, 0);
#pragma unroll
      for (int ct = 0; ct < 4; ct++)
        sacc[ct] = __builtin_amdgcn_mfma_f32_16x16x32_bf16(ak1, bq[1][ct], sacc[ct], 0, 0, 0);
#pragma unroll
      for (int ct = 0; ct < 4; ct++) {
        int i = ct * 16 + col;  // local i in [0,64)
        float e0 = fast_exp2(fmaf(sacc[ct][0], SCL, bf2f(bfrag[ct][0])));
        float e1 = fast_exp2(fmaf(sacc[ct][1], SCL, bf2f(bfrag[ct][1])));
        float e2 = fast_exp2(fmaf(sacc[ct][2], SCL, bf2f(bfrag[ct][2])));
        float e3 = fast_exp2(fmaf(sacc[ct][3], SCL, bf2f(bfrag[ct][3])));
        uint32_t u0 = __builtin_bit_cast(uint32_t, e0) + 0x8000u;
        uint32_t u1 = __builtin_bit_cast(uint32_t, e1) + 0x8000u;
        uint32_t u2 = __builtin_bit_cast(uint32_t, e2) + 0x8000u;
        uint32_t u3 = __builtin_bit_cast(uint32_t, e3) + 0x8000u;
        uint2v pk;
        pk.x = __builtin_amdgcn_perm(u1, u0, 0x07060302u);  // [bf(e1):bf(e0)]
        pk.y = __builtin_amdgcn_perm(u3, u2, 0x07060302u);  // [bf(e3):bf(e2)]
        *(uint2v*)&sP[i * 128 + ((s ^ (i & 15)) << 2)] = pk;  // conflict-free
      }
    }
    __syncthreads();  // B2: P visible; drains prefetch (had S-phase window)

    // O += P @ V ; osum += P @ 1. Wave w: O rows i in [16w,16w+16).
    const short* sVc = sV[cur];
#pragma unroll
    for (int ks = 0; ks < 4; ks++) {
      const int ch = ks * 4 + qd;
      int m = w * 16 + col;
      short4v lo = *(const short4v*)&sP[m * 128 + (((2 * ch) ^ col) << 2)];
      short4v hi = *(const short4v*)&sP[m * 128 + (((2 * ch + 1) ^ col) << 2)];
      short8 ap = __builtin_shufflevector(lo, hi, 0, 1, 2, 3, 4, 5, 6, 7);
      short8 bv[4];
#pragma unroll
      for (int ct = 0; ct < 4; ct++) {
        int d = ct * 16 + col;
        bv[ct] = *(const short8*)&sVc[d * 128 + ((ch ^ (d & 15)) << 3)];
      }
#pragma unroll
      for (int ct = 0; ct < 4; ct++)
        oacc[ct] = __builtin_amdgcn_mfma_f32_16x16x32_bf16(ap, bv[ct], oacc[ct], 0, 0, 0);
      osum = __builtin_amdgcn_mfma_f32_16x16x32_bf16(ap, onesf, osum, 0, 0, 0);
    }
  }

  // write O as attn_out [b][n][h*64+dd] bf16 ; denominator from osum
  const int b = bh >> 4;
  floatx4 inv;
#pragma unroll
  for (int r = 0; r < 4; r++) inv[r] = 1.0f / osum[r];
#pragma unroll
  for (int ct = 0; ct < 4; ct++)
#pragma unroll
    for (int r = 0; r < 4; r++) {
      int n = qt * 64 + w * 16 + qd * 4 + r;
      int dd = ct * 16 + col;
      ao[(((size_t)b * 1024 + n) << 10) + h * 64 + dd] = f2bf(oacc[ct][r] * inv[r]);
    }
}

// -------------------------------------------------------------------
extern "C" void kernel_launch(void* const* d_in, const int* in_sizes, int n_in,
                              void* d_out, int out_size, void* d_ws, size_t ws_size,
                              hipStream_t stream) {
  const float* x = (const float*)d_in[0];       // [8,1024,1024]
  const float* w_qkv = (const float*)d_in[1];   // [3072,1024]
  const float* biases = (const float*)d_in[2];  // [16,1024]
  // d_in[3] bias_idxs unused: index formula is closed-form
  const float* w_out = (const float*)d_in[4];   // [1024,1024]
  const float* b_out = (const float*)d_in[5];   // [1024]
  float* out = (float*)d_out;

  char* ws = (char*)d_ws;
  short* xb    = (short*)(ws + 0);          // 16 MB  [8192][1024]
  short* wqkvb = (short*)(ws + 16777216);   // 6 MB   [3072][1024]
  short* woutb = (short*)(ws + 23068672);   // 2 MB   [1024][1024]
  short* qb    = (short*)(ws + 25165824);   // 16 MB  [128 bh][1024][64]
  short* kb    = (short*)(ws + 41943040);   // 16 MB
  short* vtb   = (short*)(ws + 58720256);   // 16 MB  [128 bh][64][1024]
  short* aob   = (short*)(ws + 75497472);   // 16 MB  [8192][1024]
  short* biast = (short*)(ws + 92274688);   // 32 MB  [16][64][64][64][4]

  cvt_bf16<<<8192, 256, 0, stream>>>(x, xb, 8192 * 1024 / 4);
  cvt_bf16<<<3072, 256, 0, stream>>>(w_qkv, wqkvb, 3072 * 1024 / 4);
  cvt_bf16<<<1024, 256, 0, stream>>>(w_out, woutb, 1024 * 1024 / 4);
  bias_precomp<<<16384, 256, 0, stream>>>(biases, biast);

  gemm_bt<0><<<dim3(24, 64), 256, 0, stream>>>(xb, wqkvb, qb, kb, vtb, nullptr, nullptr);
  attn_fused<<<dim3(128, 16), 256, 0, stream>>>(qb, kb, vtb, biast, aob);
  gemm_bt<1><<<dim3(8, 64), 256, 0, stream>>>(aob, woutb, nullptr, nullptr, nullptr, b_out, out);
}

// Round 7
// 237.961 us; speedup vs baseline: 1.1281x; 1.1281x over previous
//
#include <hip/hip_runtime.h>
#include <stdint.h>

// MultiHeadAttention: B=8, N=1024 (32x32 tokens), E=1024, H=16, D=64.
// Pipeline: prep(cvt x/wqkv/wout + compact bias table) -> gemm_qkv -> attn -> gemm_out.
// All GEMM-shaped compute on v_mfma_f32_16x16x32_bf16 (fp32 accum).
// Fragment maps (learn_hip m89/m91/m120):
//   A: lane holds A[m=lane&15][k=8*(lane>>4)+t]
//   B: lane holds B[k=8*(lane>>4)+t][n=lane&15]
//   C/D: col=lane&15, row=4*(lane>>4)+reg
// R7: (a) revert R6's 80KB double-buffer (TLP loss beat barrier savings);
// R5 structure with sP separated from sK -> ak-hoist barrier removed:
// 3 barriers/js, 48KB LDS, 3 blocks/CU. (b) compact bias table: with RES=32,
// rj=a>>1 and cj=16(a&1)+4qd+r exactly (16+15<32, no carry), so the tile
// depends only on (|a/2-b/2|, a&1, b&1): 1MB vs 32MB -> L2-resident bias.
// (c) prep kernels fused into one launch (7 -> 4 dispatches).
// Kept (verified): conflict-free P subchunk layout, ones-column MFMA row
// sums, register-resident Q frags, 64-row Q tiles (no spill at 84 VGPR).

#define LOG2E 1.4426950408889634f

typedef __attribute__((ext_vector_type(8))) short short8;
typedef __attribute__((ext_vector_type(4))) short short4v;
typedef __attribute__((ext_vector_type(4))) float floatx4;
typedef __attribute__((ext_vector_type(2))) unsigned int uint2v;

__device__ __forceinline__ short f2bf(float f) {  // RNE, matches HW/numpy
  uint32_t u = __builtin_bit_cast(uint32_t, f);
  u = (u + 0x7FFFu + ((u >> 16) & 1u)) >> 16;
  return (short)(uint16_t)u;
}
__device__ __forceinline__ float bf2f(short s) {
  uint32_t u = ((uint32_t)(uint16_t)s) << 16;
  return __builtin_bit_cast(float, u);
}
__device__ __forceinline__ float fast_exp2(float x) {
#if __has_builtin(__builtin_amdgcn_exp2f)
  return __builtin_amdgcn_exp2f(x);
#else
  return exp2f(x);
#endif
}

__device__ __forceinline__ void gload_lds16(const short* g, short* l) {
  __builtin_amdgcn_global_load_lds(
      (const __attribute__((address_space(1))) void*)g,
      (__attribute__((address_space(3))) void*)l, 16, 0, 0);
}

// ---------------- fused prep: fp32->bf16 converts + compact bias table ----
// blocks [0,8192): x ; [8192,11264): w_qkv ; [11264,12288): w_out ;
// [12288,13312): bias tiles.
// Bias table T[h][dra][ap][bp][lane][r] = biases[h][dra*32 + |(16ap+4qd+r) -
// (16bp+col)|] * LOG2E, tile = ((h*32+dra)*2+ap)*2+bp. Valid because with
// RES=32: for j=32*ar+16*ap+4qd+r, rj=ar and cj=16ap+4qd+r exactly.
__global__ void prep(const float* __restrict__ x, const float* __restrict__ wqkv,
                     const float* __restrict__ wout, const float* __restrict__ biases,
                     short* __restrict__ xb, short* __restrict__ wqkvb,
                     short* __restrict__ woutb, short* __restrict__ biast) {
  int blk = blockIdx.x, tid = threadIdx.x;
  if (blk < 12288) {
    const float* src;
    short* dst;
    int i;
    if (blk < 8192) { src = x; dst = xb; i = blk * 256 + tid; }
    else if (blk < 11264) { src = wqkv; dst = wqkvb; i = (blk - 8192) * 256 + tid; }
    else { src = wout; dst = woutb; i = (blk - 11264) * 256 + tid; }
    float4 f = ((const float4*)src)[i];
    short4v o;
    o.x = f2bf(f.x); o.y = f2bf(f.y); o.z = f2bf(f.z); o.w = f2bf(f.w);
    ((short4v*)dst)[i] = o;
  } else {
    int tile = (blk - 12288) * 4 + (tid >> 6);  // [0, 4096)
    int lane = tid & 63, qd = lane >> 4, col = lane & 15;
    int bp = tile & 1, ap = (tile >> 1) & 1, dra = (tile >> 2) & 31, h = tile >> 7;
    int ci = 16 * bp + col;
    short4v o;
#pragma unroll
    for (int r = 0; r < 4; r++) {
      int cj = 16 * ap + 4 * qd + r;
      int dc = cj - ci; if (dc < 0) dc = -dc;
      o[r] = f2bf(biases[h * 1024 + dra * 32 + dc] * LOG2E);
    }
    *(short4v*)&biast[(size_t)tile * 256 + lane * 4] = o;
  }
}

// ---------------- 128x128 tile GEMM, C = A @ Bt^T ------------------
// A [M][1024] bf16 row-major, Bt [N][1024] bf16 row-major (= B transposed).
// MODE 0: QKV epilogue (scatter to q,k [bh][n][64] and vt [bh][64][n], bf16)
// MODE 1: out-proj epilogue (add bvec, fp32 store)
template <int MODE>
__global__ __launch_bounds__(256, 2) void gemm_bt(
    const short* __restrict__ A, const short* __restrict__ Bt,
    short* __restrict__ qo, short* __restrict__ ko, short* __restrict__ vto,
    const float* __restrict__ bvec, float* __restrict__ outf) {
  __shared__ __align__(16) short sA[128 * 64];
  __shared__ __align__(16) short sB[128 * 64];
  const int tid = threadIdx.x;
  const int w = tid >> 6, lane = tid & 63;
  const int wr = w >> 1, wc = w & 1;
  const int bm = blockIdx.y, bn = blockIdx.x;
  const int qd = lane >> 4, col = lane & 15;

  floatx4 acc[4][4] = {};
  const int rowA0 = bm * 128, rowB0 = bn * 128;
  const int ciw = w * 256;

  for (int kk = 0; kk < 1024; kk += 64) {
    __syncthreads();
#pragma unroll
    for (int n = 0; n < 4; n++) {
      int ci = ciw + n * 64 + lane;
      int r = ci >> 3, c = (ci & 7) ^ (r & 7);
      gload_lds16(A + (size_t)(rowA0 + r) * 1024 + kk + c * 8, &sA[ci * 8]);
    }
#pragma unroll
    for (int n = 0; n < 4; n++) {
      int ci = ciw + n * 64 + lane;
      int r = ci >> 3, c = (ci & 7) ^ (r & 7);
      gload_lds16(Bt + (size_t)(rowB0 + r) * 1024 + kk + c * 8, &sB[ci * 8]);
    }
    __syncthreads();

#pragma unroll
    for (int ks = 0; ks < 2; ks++) {
      const int ch = qd + ks * 4;
      short8 af[4], bff[4];
#pragma unroll
      for (int rt = 0; rt < 4; rt++) {
        int r = wr * 64 + rt * 16 + col;
        af[rt] = *(const short8*)&sA[r * 64 + ((ch ^ (r & 7)) << 3)];
      }
#pragma unroll
      for (int ct = 0; ct < 4; ct++) {
        int r = wc * 64 + ct * 16 + col;
        bff[ct] = *(const short8*)&sB[r * 64 + ((ch ^ (r & 7)) << 3)];
      }
#pragma unroll
      for (int rt = 0; rt < 4; rt++)
#pragma unroll
        for (int ct = 0; ct < 4; ct++)
          acc[rt][ct] = __builtin_amdgcn_mfma_f32_16x16x32_bf16(af[rt], bff[ct], acc[rt][ct], 0, 0, 0);
    }
  }

  if (MODE == 0) {
    if (bn >= 16) {
      // V region (block-uniform): pack 4 consecutive n into b64 scatters
#pragma unroll
      for (int rt = 0; rt < 4; rt++) {
#pragma unroll
        for (int ct = 0; ct < 4; ct++) {
          int Cg = bn * 128 + wc * 64 + ct * 16 + col;
          int e = Cg & 1023, h = e >> 6, dd = e & 63;
          short4v pv;
#pragma unroll
          for (int r = 0; r < 4; r++) pv[r] = f2bf(acc[rt][ct][r]);
          int R0 = bm * 128 + wr * 64 + rt * 16 + qd * 4;
          int b = R0 >> 10, n0 = R0 & 1023;
          int bh = b * 16 + h;
          *(short4v*)&vto[((size_t)bh * 64 + dd) * 1024 + n0] = pv;
        }
      }
    } else {
#pragma unroll
      for (int rt = 0; rt < 4; rt++) {
#pragma unroll
        for (int ct = 0; ct < 4; ct++) {
          int Cg = bn * 128 + wc * 64 + ct * 16 + col;
          int which = Cg >> 10, e = Cg & 1023, h = e >> 6, dd = e & 63;
#pragma unroll
          for (int r = 0; r < 4; r++) {
            int R = bm * 128 + wr * 64 + rt * 16 + qd * 4 + r;
            int b = R >> 10, n = R & 1023;
            int bh = b * 16 + h;
            short v = f2bf(acc[rt][ct][r]);
            if (which == 0)
              qo[((size_t)bh * 1024 + n) * 64 + dd] = v;
            else
              ko[((size_t)bh * 1024 + n) * 64 + dd] = v;
          }
        }
      }
    }
  } else {
#pragma unroll
    for (int rt = 0; rt < 4; rt++)
#pragma unroll
      for (int ct = 0; ct < 4; ct++) {
        int Cg = bn * 128 + wc * 64 + ct * 16 + col;
        float bo = bvec[Cg];
#pragma unroll
        for (int r = 0; r < 4; r++) {
          int R = bm * 128 + wr * 64 + rt * 16 + qd * 4 + r;
          outf[(size_t)R * 1024 + Cg] = acc[rt][ct][r] + bo;
        }
      }
  }
}

// ---------------- fused attention (flash-style, no max: logits bounded) ----
// grid.x = bh (128), grid.y = qt (16). Per block: Q-tile 64 rows; 8 K/V tiles
// of 128. S^T = K Q^T (j rows, i cols); Q B-frags in registers.
// LDS: sK 16KB (XOR-8), sVt 16KB (XOR-16), sP 16KB (subchunk layout; Q
// staging temp at start). 48KB -> 3 blocks/CU. 3 barriers per js.
__global__ __launch_bounds__(256, 3) void attn_fused(
    const short* __restrict__ q, const short* __restrict__ k,
    const short* __restrict__ vt, const short* __restrict__ biast,
    short* __restrict__ ao) {
  __shared__ __align__(16) short sK[128 * 64];
  __shared__ __align__(16) short sVt[64 * 128];
  __shared__ __align__(16) short sP[64 * 128];
  const int tid = threadIdx.x, w = tid >> 6, lane = tid & 63;
  const int bh = blockIdx.x, qt = blockIdx.y;
  const int h = bh & 15;
  const int qd = lane >> 4, col = lane & 15;
  const short* qb = q + (size_t)bh * 65536;
  const short* kb = k + (size_t)bh * 65536;
  const short* vb = vt + (size_t)bh * 65536;
  const int ciw = w * 256;

  // stage Q tile (64 rows at qt*64) into sP temp, XOR-8, hoist to regs
#pragma unroll
  for (int n = 0; n < 2; n++) {
    int ci = w * 128 + n * 64 + lane;
    int r = ci >> 3, c = (ci & 7) ^ (r & 7);
    gload_lds16(qb + (size_t)(qt * 64 + r) * 64 + c * 8, &sP[ci * 8]);
  }
  __syncthreads();
  short8 bq[2][4];  // [ks][ct] B-frags of Q, js-invariant (32 VGPRs)
#pragma unroll
  for (int ks = 0; ks < 2; ks++) {
    const int ch = qd + ks * 4;
#pragma unroll
    for (int ct = 0; ct < 4; ct++) {
      int r2 = ct * 16 + col;
      bq[ks][ct] = *(const short8*)&sP[r2 * 64 + ((ch ^ (r2 & 7)) << 3)];
    }
  }

  // ones B-frag for row-sum MFMA (bf16 1.0 = 0x3F80)
  short8 onesf;
#pragma unroll
  for (int t = 0; t < 8; t++) onesf[t] = (short)0x3F80;

  floatx4 oacc[4] = {};  // [d-tile ct], O rows i in [16w,16w+16)
  floatx4 osum = {};
  const float SCL = 0.125f * LOG2E;

  for (int js = 0; js < 8; js++) {
    __syncthreads();  // B1: prior PV reads done (js=0: Q-frag reads done)
    // stage K tile [128][64] into sK, XOR-8
#pragma unroll
    for (int n = 0; n < 4; n++) {
      int ci = ciw + n * 64 + lane;
      int r = ci >> 3, c = (ci & 7) ^ (r & 7);
      gload_lds16(kb + (size_t)(js * 128 + r) * 64 + c * 8, &sK[ci * 8]);
    }
    // stage Vt tile [64][128] into sVt, XOR-16
#pragma unroll
    for (int n = 0; n < 4; n++) {
      int ci = ciw + n * 64 + lane;
      int r = ci >> 4, c = (ci & 15) ^ (r & 15);
      gload_lds16(vb + (size_t)r * 1024 + js * 128 + c * 8, &sVt[ci * 8]);
    }
    __syncthreads();  // B2: staged

    // S^T tiles (wave w: j rows [32w,32w+32), i cols 0..64) + softmax + P
#pragma unroll
    for (int rt = 0; rt < 2; rt++) {
      const int a = js * 8 + w * 2 + rt;    // global j-tile
      const int s = w * 8 + rt * 4 + qd;    // P subchunk index (j>>2)
      const int ar = a >> 1, ap = a & 1;
      short4v bfrag[4];
#pragma unroll
      for (int ct = 0; ct < 4; ct++) {
        int b = qt * 4 + ct;                 // global i-tile
        int dra = ar - (b >> 1); if (dra < 0) dra = -dra;
        int tile = ((h * 32 + dra) * 2 + ap) * 2 + (b & 1);
        bfrag[ct] = *(const short4v*)&biast[(size_t)tile * 256 + lane * 4];
      }
      const int r = w * 32 + rt * 16 + col;
      short8 ak0 = *(const short8*)&sK[r * 64 + (((qd + 0) ^ (r & 7)) << 3)];
      short8 ak1 = *(const short8*)&sK[r * 64 + (((qd + 4) ^ (r & 7)) << 3)];
      floatx4 sacc[4] = {};
#pragma unroll
      for (int ct = 0; ct < 4; ct++)
        sacc[ct] = __builtin_amdgcn_mfma_f32_16x16x32_bf16(ak0, bq[0][ct], sacc[ct], 0, 0, 0);
#pragma unroll
      for (int ct = 0; ct < 4; ct++)
        sacc[ct] = __builtin_amdgcn_mfma_f32_16x16x32_bf16(ak1, bq[1][ct], sacc[ct], 0, 0, 0);
#pragma unroll
      for (int ct = 0; ct < 4; ct++) {
        int i = ct * 16 + col;  // local i in [0,64)
        float e0 = fast_exp2(fmaf(sacc[ct][0], SCL, bf2f(bfrag[ct][0])));
        float e1 = fast_exp2(fmaf(sacc[ct][1], SCL, bf2f(bfrag[ct][1])));
        float e2 = fast_exp2(fmaf(sacc[ct][2], SCL, bf2f(bfrag[ct][2])));
        float e3 = fast_exp2(fmaf(sacc[ct][3], SCL, bf2f(bfrag[ct][3])));
        uint32_t u0 = __builtin_bit_cast(uint32_t, e0) + 0x8000u;
        uint32_t u1 = __builtin_bit_cast(uint32_t, e1) + 0x8000u;
        uint32_t u2 = __builtin_bit_cast(uint32_t, e2) + 0x8000u;
        uint32_t u3 = __builtin_bit_cast(uint32_t, e3) + 0x8000u;
        uint2v pk;
        pk.x = __builtin_amdgcn_perm(u1, u0, 0x07060302u);  // [bf(e1):bf(e0)]
        pk.y = __builtin_amdgcn_perm(u3, u2, 0x07060302u);  // [bf(e3):bf(e2)]
        *(uint2v*)&sP[i * 128 + ((s ^ (i & 15)) << 2)] = pk;  // conflict-free
      }
    }
    __syncthreads();  // B3: P visible cross-wave

    // O += P @ V ; osum += P @ 1. Wave w: O rows i in [16w,16w+16).
#pragma unroll
    for (int ks = 0; ks < 4; ks++) {
      const int ch = ks * 4 + qd;
      int m = w * 16 + col;
      short4v lo = *(const short4v*)&sP[m * 128 + (((2 * ch) ^ col) << 2)];
      short4v hi = *(const short4v*)&sP[m * 128 + (((2 * ch + 1) ^ col) << 2)];
      short8 ap = __builtin_shufflevector(lo, hi, 0, 1, 2, 3, 4, 5, 6, 7);
      short8 bv[4];
#pragma unroll
      for (int ct = 0; ct < 4; ct++) {
        int d = ct * 16 + col;
        bv[ct] = *(const short8*)&sVt[d * 128 + ((ch ^ (d & 15)) << 3)];
      }
#pragma unroll
      for (int ct = 0; ct < 4; ct++)
        oacc[ct] = __builtin_amdgcn_mfma_f32_16x16x32_bf16(ap, bv[ct], oacc[ct], 0, 0, 0);
      osum = __builtin_amdgcn_mfma_f32_16x16x32_bf16(ap, onesf, osum, 0, 0, 0);
    }
  }

  // write O as attn_out [b][n][h*64+dd] bf16 ; denominator from osum
  const int b = bh >> 4;
  floatx4 inv;
#pragma unroll
  for (int r = 0; r < 4; r++) inv[r] = 1.0f / osum[r];
#pragma unroll
  for (int ct = 0; ct < 4; ct++)
#pragma unroll
    for (int r = 0; r < 4; r++) {
      int n = qt * 64 + w * 16 + qd * 4 + r;
      int dd = ct * 16 + col;
      ao[(((size_t)b * 1024 + n) << 10) + h * 64 + dd] = f2bf(oacc[ct][r] * inv[r]);
    }
}

// -------------------------------------------------------------------
extern "C" void kernel_launch(void* const* d_in, const int* in_sizes, int n_in,
                              void* d_out, int out_size, void* d_ws, size_t ws_size,
                              hipStream_t stream) {
  const float* x = (const float*)d_in[0];       // [8,1024,1024]
  const float* w_qkv = (const float*)d_in[1];   // [3072,1024]
  const float* biases = (const float*)d_in[2];  // [16,1024]
  // d_in[3] bias_idxs unused: index formula is closed-form
  const float* w_out = (const float*)d_in[4];   // [1024,1024]
  const float* b_out = (const float*)d_in[5];   // [1024]
  float* out = (float*)d_out;

  char* ws = (char*)d_ws;
  short* xb    = (short*)(ws + 0);          // 16 MB  [8192][1024]
  short* wqkvb = (short*)(ws + 16777216);   // 6 MB   [3072][1024]
  short* woutb = (short*)(ws + 23068672);   // 2 MB   [1024][1024]
  short* qb    = (short*)(ws + 25165824);   // 16 MB  [128 bh][1024][64]
  short* kb    = (short*)(ws + 41943040);   // 16 MB
  short* vtb   = (short*)(ws + 58720256);   // 16 MB  [128 bh][64][1024]
  short* aob   = (short*)(ws + 75497472);   // 16 MB  [8192][1024]
  short* biast = (short*)(ws + 92274688);   // 1 MB   [16][32][2][2][64][4]

  prep<<<13312, 256, 0, stream>>>(x, w_qkv, w_out, biases, xb, wqkvb, woutb, biast);
  gemm_bt<0><<<dim3(24, 64), 256, 0, stream>>>(xb, wqkvb, qb, kb, vtb, nullptr, nullptr);
  attn_fused<<<dim3(128, 16), 256, 0, stream>>>(qb, kb, vtb, biast, aob);
  gemm_bt<1><<<dim3(8, 64), 256, 0, stream>>>(aob, woutb, nullptr, nullptr, nullptr, b_out, out);
}